// Round 2
// baseline (14995.683 us; speedup 1.0000x reference)
//
#include <hip/hip_runtime.h>

#define BB 64
#define TT 1024
#define DD 512
#define BT (BB*TT)

// ===========================================================================
// GEMM: C[bt, e'] = sum_d x[bt,d] * W[e',d] + bias[e']   (all f32)
//  e' <  512 : W row = tau_w[e'] (row stride 1024), dst = xp (spike region of out)
//  e' >= 512 : W row = mem_w[e'-512] (row stride 512), dst = m (ws)
// Tile 128(M) x 64(N), WG 256 thr, micro 4x8, BK=32, reg-prefetch staging.
// ===========================================================================
__global__ __launch_bounds__(256, 2) void gemm_kernel(
    const float* __restrict__ x, const float* __restrict__ tau_w,
    const float* __restrict__ tau_b, const float* __restrict__ mem_w,
    const float* __restrict__ mem_b, float* __restrict__ xp, float* __restrict__ mm)
{
    __shared__ float As[32][132];   // k-major, pad to 132 (16B-aligned rows)
    __shared__ float Bs[32][68];

    const int tid  = threadIdx.x;
    const int bt0  = blockIdx.x * 128;
    const bool isxp = (blockIdx.y < 8);
    const float* W       = isxp ? tau_w : mem_w;
    const int    wstride = isxp ? 1024 : 512;
    const int    e0      = isxp ? blockIdx.y * 64 : blockIdx.y * 64 - 512;
    const float* bias    = isxp ? tau_b : mem_b;
    float*       dst     = isxp ? xp : mm;

    const int tm = tid & 31, tn = tid >> 5;   // micro-tile coords
    const int lr = tid >> 3, lc = tid & 7;    // loader coords

    float bias_r[8];
#pragma unroll
    for (int ni = 0; ni < 8; ni++) bias_r[ni] = bias[e0 + tn * 8 + ni];

    float acc[4][8] = {};
    float4 pa[4], pb[2];

#pragma unroll
    for (int j = 0; j < 4; j++)
        pa[j] = *(const float4*)(x + (size_t)(bt0 + lr + 32 * j) * DD + lc * 4);
#pragma unroll
    for (int j = 0; j < 2; j++)
        pb[j] = *(const float4*)(W + (size_t)(e0 + lr + 32 * j) * wstride + lc * 4);

    for (int kb = 0; kb < DD; kb += 32) {
#pragma unroll
        for (int j = 0; j < 4; j++) {
            As[lc * 4 + 0][lr + 32 * j] = pa[j].x;
            As[lc * 4 + 1][lr + 32 * j] = pa[j].y;
            As[lc * 4 + 2][lr + 32 * j] = pa[j].z;
            As[lc * 4 + 3][lr + 32 * j] = pa[j].w;
        }
#pragma unroll
        for (int j = 0; j < 2; j++) {
            Bs[lc * 4 + 0][lr + 32 * j] = pb[j].x;
            Bs[lc * 4 + 1][lr + 32 * j] = pb[j].y;
            Bs[lc * 4 + 2][lr + 32 * j] = pb[j].z;
            Bs[lc * 4 + 3][lr + 32 * j] = pb[j].w;
        }
        __syncthreads();
        if (kb + 32 < DD) {
#pragma unroll
            for (int j = 0; j < 4; j++)
                pa[j] = *(const float4*)(x + (size_t)(bt0 + lr + 32 * j) * DD + kb + 32 + lc * 4);
#pragma unroll
            for (int j = 0; j < 2; j++)
                pb[j] = *(const float4*)(W + (size_t)(e0 + lr + 32 * j) * wstride + kb + 32 + lc * 4);
        }
#pragma unroll
        for (int k = 0; k < 32; k++) {
            float4 av  = *(const float4*)&As[k][tm * 4];
            float4 bv0 = *(const float4*)&Bs[k][tn * 8];
            float4 bv1 = *(const float4*)&Bs[k][tn * 8 + 4];
            float a_[4] = {av.x, av.y, av.z, av.w};
            float b_[8] = {bv0.x, bv0.y, bv0.z, bv0.w, bv1.x, bv1.y, bv1.z, bv1.w};
#pragma unroll
            for (int mi = 0; mi < 4; mi++)
#pragma unroll
                for (int ni = 0; ni < 8; ni++)
                    acc[mi][ni] = fmaf(a_[mi], b_[ni], acc[mi][ni]);
        }
        __syncthreads();
    }

#pragma unroll
    for (int mi = 0; mi < 4; mi++) {
        const int row = bt0 + tm * 4 + mi;
        float o[8];
#pragma unroll
        for (int ni = 0; ni < 8; ni++) o[ni] = __fadd_rn(acc[mi][ni], bias_r[ni]);
        float4 s0 = {o[0], o[1], o[2], o[3]};
        float4 s1 = {o[4], o[5], o[6], o[7]};
        *(float4*)(dst + (size_t)row * DD + e0 + tn * 8)     = s0;
        *(float4*)(dst + (size_t)row * DD + e0 + tn * 8 + 4) = s1;
    }
}

// ===========================================================================
// Scan: 4 WGs per batch (256 WGs total, 1 per CU — all co-resident).
// WG (b,p) owns e in [p*128,(p+1)*128). Thread = (k-chunk c = wave&3,
// local_e = (wave>>2)*64+lane). 128 f32 Wt weights per thread in VGPRs.
// tau exchanged per step via global double-buffer + device-scope flags.
// ===========================================================================
__global__ __launch_bounds__(512, 2) void scan_kernel(
    const float* __restrict__ tau_w,
    float* __restrict__ xp_sp,          // out base: holds xp, overwritten w/ spikes
    const float* __restrict__ mm,       // ws: m (B,T,D)
    const float* __restrict__ thrp,
    float* __restrict__ tau_out, float* __restrict__ v_out,
    float* __restrict__ taug,           // ws: 2 slots x 64 x 512
    unsigned int* __restrict__ flags)   // ws: 64 x 4, zeroed
{
    __shared__ float tau_lds[DD];
    __shared__ float partial[4][128];

    const int wg = blockIdx.x;
    const int b = wg >> 2, p = wg & 3;
    const int tid = threadIdx.x;
    const int w = tid >> 6, lane = tid & 63;
    const int c  = w & 3;
    const int le = ((w >> 2) << 6) + lane;   // 0..127
    const int ge = p * 128 + le;             // 0..511

    // resident weights: wv[j] = Wt[ge][c*128 + 4j .. +3] = tau_w[ge*1024 + 512 + ...]
    float4 wv[32];
    const float4* wrow = (const float4*)(tau_w + (size_t)ge * 1024 + 512 + c * 128);
#pragma unroll
    for (int j = 0; j < 32; j++) wv[j] = wrow[j];

    if (tid < DD) tau_lds[tid] = 1.0f;       // tau_0 = 1

    const float thr = thrp[0];
    const bool owner = (c == 0);
    float v = 0.0f, tau_keep = 1.0f;
    const size_t baseio = (size_t)b * TT * DD + ge;

    __syncthreads();

    for (int i = 0; i < TT; i++) {
        if (i > 0) {
            if (tid < 3) {
                const int q = (p + 1 + tid) & 3;
                while (__hip_atomic_load(&flags[b * 4 + q], __ATOMIC_ACQUIRE,
                                         __HIP_MEMORY_SCOPE_AGENT) < (unsigned)i) {}
            }
            __syncthreads();
            if (tid < 384) {   // gather 3 remote 128-slices of tau_i
                const int s = tid >> 7, j = tid & 127;
                const int q = (p + 1 + s) & 3;
                tau_lds[q * 128 + j] =
                    taug[(size_t)(i & 1) * (64 * 512) + b * 512 + q * 128 + j];
            }
            __syncthreads();
        }

        float xpv = 0.0f, mv = 0.0f;
        if (owner) {                          // issue early; in flight during dot
            xpv = xp_sp[baseio + (size_t)i * DD];
            mv  = mm  [baseio + (size_t)i * DD];
        }

        float a0 = 0.f, a1 = 0.f, a2 = 0.f, a3 = 0.f;
        const float4* tl = (const float4*)&tau_lds[c * 128];
#pragma unroll
        for (int j = 0; j < 32; j++) {
            float4 t4 = tl[j];                // wave-uniform addr -> broadcast
            a0 = fmaf(wv[j].x, t4.x, a0);
            a1 = fmaf(wv[j].y, t4.y, a1);
            a2 = fmaf(wv[j].z, t4.z, a2);
            a3 = fmaf(wv[j].w, t4.w, a3);
        }
        partial[c][le] = (a0 + a1) + (a2 + a3);
        __syncthreads();

        if (owner) {
            float dotv = (partial[0][le] + partial[1][le]) +
                         (partial[2][le] + partial[3][le]);
            float z     = __fadd_rn(xpv, dotv);
            float enz   = expf(-z);
            float tau_n = 1.0f / __fadd_rn(1.0f, enz);
            tau_keep = tau_n;
            float tpe   = __fadd_rn(tau_n, 1e-6f);
            float alpha = expf(-1.0f / tpe);
            float vn = __fadd_rn(__fmul_rn(alpha, v),
                                 __fmul_rn(__fsub_rn(1.0f, alpha), mv));
            bool s = (vn >= thr);
            xp_sp[baseio + (size_t)i * DD] = s ? 1.0f : 0.0f;   // spike (overwrites xp)
            v = s ? 0.0f : vn;
            tau_lds[ge] = tau_n;              // own slice for next step's dot
            if (i < TT - 1)
                taug[(size_t)((i + 1) & 1) * (64 * 512) + b * 512 + ge] = tau_n;
        }
        __syncthreads();
        if (i < TT - 1 && tid == 0) {
            __threadfence();   // agent-scope: flush WG writes to coherence point
            __hip_atomic_store(&flags[b * 4 + p], (unsigned)(i + 1),
                               __ATOMIC_RELEASE, __HIP_MEMORY_SCOPE_AGENT);
        }
    }

    if (owner) {
        tau_out[b * DD + ge] = tau_keep;
        v_out  [b * DD + ge] = v;
    }
}

extern "C" void kernel_launch(void* const* d_in, const int* in_sizes, int n_in,
                              void* d_out, int out_size, void* d_ws, size_t ws_size,
                              hipStream_t stream) {
    (void)in_sizes; (void)n_in; (void)out_size; (void)ws_size;
    const float* x     = (const float*)d_in[0];
    const float* tau_w = (const float*)d_in[1];
    const float* tau_b = (const float*)d_in[2];
    const float* mem_w = (const float*)d_in[3];
    const float* mem_b = (const float*)d_in[4];
    const float* thr   = (const float*)d_in[5];
    float* out = (float*)d_out;

    float* mm            = (float*)d_ws;                       // 134,217,728 B
    float* taug          = mm + (size_t)BT * DD;               // 262,144 B
    unsigned int* flags  = (unsigned int*)(taug + 2 * 64 * 512); // 1,024 B

    hipMemsetAsync(flags, 0, 64 * 4 * sizeof(unsigned int), stream);

    // xp goes into out's spikes region (exactly (B,T,D) f32); scan overwrites it.
    gemm_kernel<<<dim3(512, 16), 256, 0, stream>>>(x, tau_w, tau_b, mem_w, mem_b,
                                                   out, mm);
    scan_kernel<<<256, 512, 0, stream>>>(tau_w, out, mm, thr,
                                         out + (size_t)BT * DD,
                                         out + (size_t)BT * DD + (size_t)BB * DD,
                                         taug, flags);
}

// Round 5
// 4342.553 us; speedup vs baseline: 3.4532x; 3.4532x over previous
//
#include <hip/hip_runtime.h>

#define BB 64
#define TT 1024
#define DD 512
#define BT (BB*TT)

typedef float f4 __attribute__((ext_vector_type(4)));

// ===========================================================================
// GEMM: C[bt, e'] = sum_d x[bt,d] * W[e',d] + bias[e']   (all f32)
// (unchanged from round 2 — verified absmax 0.0)
// ===========================================================================
__global__ __launch_bounds__(256, 2) void gemm_kernel(
    const float* __restrict__ x, const float* __restrict__ tau_w,
    const float* __restrict__ tau_b, const float* __restrict__ mem_w,
    const float* __restrict__ mem_b, float* __restrict__ xp, float* __restrict__ mm)
{
    __shared__ float As[32][132];
    __shared__ float Bs[32][68];

    const int tid  = threadIdx.x;
    const int bt0  = blockIdx.x * 128;
    const bool isxp = (blockIdx.y < 8);
    const float* W       = isxp ? tau_w : mem_w;
    const int    wstride = isxp ? 1024 : 512;
    const int    e0      = isxp ? blockIdx.y * 64 : blockIdx.y * 64 - 512;
    const float* bias    = isxp ? tau_b : mem_b;
    float*       dst     = isxp ? xp : mm;

    const int tm = tid & 31, tn = tid >> 5;
    const int lr = tid >> 3, lc = tid & 7;

    float bias_r[8];
#pragma unroll
    for (int ni = 0; ni < 8; ni++) bias_r[ni] = bias[e0 + tn * 8 + ni];

    float acc[4][8] = {};
    float4 pa[4], pb[2];

#pragma unroll
    for (int j = 0; j < 4; j++)
        pa[j] = *(const float4*)(x + (size_t)(bt0 + lr + 32 * j) * DD + lc * 4);
#pragma unroll
    for (int j = 0; j < 2; j++)
        pb[j] = *(const float4*)(W + (size_t)(e0 + lr + 32 * j) * wstride + lc * 4);

    for (int kb = 0; kb < DD; kb += 32) {
#pragma unroll
        for (int j = 0; j < 4; j++) {
            As[lc * 4 + 0][lr + 32 * j] = pa[j].x;
            As[lc * 4 + 1][lr + 32 * j] = pa[j].y;
            As[lc * 4 + 2][lr + 32 * j] = pa[j].z;
            As[lc * 4 + 3][lr + 32 * j] = pa[j].w;
        }
#pragma unroll
        for (int j = 0; j < 2; j++) {
            Bs[lc * 4 + 0][lr + 32 * j] = pb[j].x;
            Bs[lc * 4 + 1][lr + 32 * j] = pb[j].y;
            Bs[lc * 4 + 2][lr + 32 * j] = pb[j].z;
            Bs[lc * 4 + 3][lr + 32 * j] = pb[j].w;
        }
        __syncthreads();
        if (kb + 32 < DD) {
#pragma unroll
            for (int j = 0; j < 4; j++)
                pa[j] = *(const float4*)(x + (size_t)(bt0 + lr + 32 * j) * DD + kb + 32 + lc * 4);
#pragma unroll
            for (int j = 0; j < 2; j++)
                pb[j] = *(const float4*)(W + (size_t)(e0 + lr + 32 * j) * wstride + kb + 32 + lc * 4);
        }
#pragma unroll
        for (int k = 0; k < 32; k++) {
            float4 av  = *(const float4*)&As[k][tm * 4];
            float4 bv0 = *(const float4*)&Bs[k][tn * 8];
            float4 bv1 = *(const float4*)&Bs[k][tn * 8 + 4];
            float a_[4] = {av.x, av.y, av.z, av.w};
            float b_[8] = {bv0.x, bv0.y, bv0.z, bv0.w, bv1.x, bv1.y, bv1.z, bv1.w};
#pragma unroll
            for (int mi = 0; mi < 4; mi++)
#pragma unroll
                for (int ni = 0; ni < 8; ni++)
                    acc[mi][ni] = fmaf(a_[mi], b_[ni], acc[mi][ni]);
        }
        __syncthreads();
    }

#pragma unroll
    for (int mi = 0; mi < 4; mi++) {
        const int row = bt0 + tm * 4 + mi;
        float o[8];
#pragma unroll
        for (int ni = 0; ni < 8; ni++) o[ni] = __fadd_rn(acc[mi][ni], bias_r[ni]);
        float4 s0 = {o[0], o[1], o[2], o[3]};
        float4 s1 = {o[4], o[5], o[6], o[7]};
        *(float4*)(dst + (size_t)row * DD + e0 + tn * 8)     = s0;
        *(float4*)(dst + (size_t)row * DD + e0 + tn * 8 + 4) = s1;
    }
}

// ===========================================================================
// Scan: 4 WGs per batch, 256 WGs co-resident. Weights resident in VGPRs.
// Cross-WG tau exchange via agent-scope RMW atomics only (execute at MALL,
// no cache-maintenance ops -> warm caches). KEY FIX vs R4: the producer's
// taug exchange uses the RETURNING (sc0) form and the old value is consumed
// before __syncthreads -> the RMW has provably executed at the MALL before
// the flag RMW is issued. Closes the data/flag arrival-order race that
// graph-replay timing exposed.
// ===========================================================================
__global__ __launch_bounds__(512, 1) void scan_kernel(
    const float* __restrict__ tau_w,
    float* __restrict__ xp_sp,          // out base: xp in, spikes out
    const float* __restrict__ mm,       // ws: m (B,T,D)
    const float* __restrict__ thrp,
    float* __restrict__ tau_out, float* __restrict__ v_out,
    unsigned int* __restrict__ taug,    // ws: 2 x 64 x 512 (f32 bits)
    unsigned int* __restrict__ flags)   // ws: 64 x 4, zeroed
{
    __shared__ float tau_lds[DD];
    __shared__ float partial[4][128];

    const int wg = blockIdx.x;
    const int b = wg >> 2, p = wg & 3;
    const int tid = threadIdx.x;
    const int w = tid >> 6, lane = tid & 63;
    const int c  = w & 3;                    // k-chunk
    const int le = ((w >> 2) << 6) + lane;   // 0..127
    const int ge = p * 128 + le;             // owned e

    // resident weights: Wt[ge][c*128 .. c*128+127] as 128 scalars
    float wv[128];
    {
        const float4* wrow = (const float4*)(tau_w + (size_t)ge * 1024 + 512 + c * 128);
#pragma unroll
        for (int j = 0; j < 32; j++) {
            float4 t = wrow[j];
            wv[4 * j + 0] = t.x; wv[4 * j + 1] = t.y;
            wv[4 * j + 2] = t.z; wv[4 * j + 3] = t.w;
        }
    }
#pragma unroll
    for (int j = 0; j < 128; j++) asm volatile("" : "+v"(wv[j]));  // keep live

    if (tid < DD) tau_lds[tid] = 1.0f;

    const float thr = thrp[0];
    const bool owner = (c == 0);
    float v = 0.0f, tau_keep = 1.0f;
    const size_t baseio = (size_t)b * TT * DD + ge;

    __syncthreads();

    for (int i = 0; i < TT; i++) {
        // prefetch step inputs (independent of remote tau; in flight during spin)
        float xpv = 0.0f, mv = 0.0f;
        if (owner) {
            xpv = xp_sp[baseio + (size_t)i * DD];
            mv  = mm  [baseio + (size_t)i * DD];
        }

        if (i > 0) {
            if (tid < 3) {  // RMW spin: executes at MALL, always fresh
                const int q = (p + 1 + tid) & 3;
                while (__hip_atomic_fetch_add(&flags[b * 4 + q], 0u,
                                              __ATOMIC_RELAXED,
                                              __HIP_MEMORY_SCOPE_AGENT) < (unsigned)i) {}
            }
            __syncthreads();
            if (tid < 384) {  // RMW gather of 3 remote 128-slices: fresh at MALL
                const int s = tid >> 7, j = tid & 127;
                const int q = (p + 1 + s) & 3;
                unsigned int raw = __hip_atomic_fetch_add(
                    &taug[(size_t)(i & 1) * (64 * 512) + b * 512 + q * 128 + j],
                    0u, __ATOMIC_RELAXED, __HIP_MEMORY_SCOPE_AGENT);
                tau_lds[q * 128 + j] = __uint_as_float(raw);
            }
            __syncthreads();
        }

        float a0 = 0.f, a1 = 0.f, a2 = 0.f, a3 = 0.f;
        {
            const f4* tl = (const f4*)&tau_lds[c * 128];
#pragma unroll
            for (int j = 0; j < 32; j++) {
                f4 t4 = tl[j];                // wave-uniform addr -> broadcast
                a0 = fmaf(wv[4 * j + 0], t4.x, a0);
                a1 = fmaf(wv[4 * j + 1], t4.y, a1);
                a2 = fmaf(wv[4 * j + 2], t4.z, a2);
                a3 = fmaf(wv[4 * j + 3], t4.w, a3);
            }
        }
        partial[c][le] = (a0 + a1) + (a2 + a3);
        __syncthreads();

        if (owner) {
            float dotv = (partial[0][le] + partial[1][le]) +
                         (partial[2][le] + partial[3][le]);
            float z     = __fadd_rn(xpv, dotv);
            float enz   = expf(-z);
            float tau_n = 1.0f / __fadd_rn(1.0f, enz);
            tau_keep = tau_n;
            float tpe   = __fadd_rn(tau_n, 1e-6f);
            float alpha = expf(-1.0f / tpe);
            float vn = __fadd_rn(__fmul_rn(alpha, v),
                                 __fmul_rn(__fsub_rn(1.0f, alpha), mv));
            bool s = (vn >= thr);
            xp_sp[baseio + (size_t)i * DD] = s ? 1.0f : 0.0f;
            v = s ? 0.0f : vn;
            tau_lds[ge] = tau_n;              // own slice for next step
            if (i < TT - 1) {
                // sc0 (returning) exchange: consuming `old` forces the wave to
                // wait until the RMW has EXECUTED AT THE MALL, before barrier.
                unsigned int old = __hip_atomic_exchange(
                    &taug[(size_t)((i + 1) & 1) * (64 * 512) + b * 512 + ge],
                    __float_as_uint(tau_n),
                    __ATOMIC_RELAXED, __HIP_MEMORY_SCOPE_AGENT);
                asm volatile("" :: "v"(old));   // sink: keep sc0 + force wait
            }
        }
        // all owner-wave data RMWs are complete at MALL before any wave exits
        __syncthreads();
        if (i < TT - 1 && tid == 0)
            __hip_atomic_exchange(&flags[b * 4 + p], (unsigned)(i + 1),
                                  __ATOMIC_RELAXED, __HIP_MEMORY_SCOPE_AGENT);
    }

    if (owner) {
        tau_out[b * DD + ge] = tau_keep;
        v_out  [b * DD + ge] = v;
    }
}

extern "C" void kernel_launch(void* const* d_in, const int* in_sizes, int n_in,
                              void* d_out, int out_size, void* d_ws, size_t ws_size,
                              hipStream_t stream) {
    (void)in_sizes; (void)n_in; (void)out_size; (void)ws_size;
    const float* x     = (const float*)d_in[0];
    const float* tau_w = (const float*)d_in[1];
    const float* tau_b = (const float*)d_in[2];
    const float* mem_w = (const float*)d_in[3];
    const float* mem_b = (const float*)d_in[4];
    const float* thr   = (const float*)d_in[5];
    float* out = (float*)d_out;

    float* mm            = (float*)d_ws;
    unsigned int* taug   = (unsigned int*)(mm + (size_t)BT * DD);
    unsigned int* flags  = taug + 2 * 64 * 512;

    hipMemsetAsync(flags, 0, 64 * 4 * sizeof(unsigned int), stream);

    gemm_kernel<<<dim3(512, 16), 256, 0, stream>>>(x, tau_w, tau_b, mem_w, mem_b,
                                                   out, mm);
    scan_kernel<<<256, 512, 0, stream>>>(tau_w, out, mm, thr,
                                         out + (size_t)BT * DD,
                                         out + (size_t)BT * DD + (size_t)BB * DD,
                                         taug, flags);
}

// Round 6
// 3181.983 us; speedup vs baseline: 4.7127x; 1.3647x over previous
//
#include <hip/hip_runtime.h>

#define BB 64
#define TT 1024
#define DD 512
#define BT (BB*TT)

#define SENT 0xFFFFFFFFFFFFFFFFULL
#define TAUG_WORDS (2ULL * 64 * 4 * 192)   // parity x (b,p) x 192 u64 slots

typedef float f4 __attribute__((ext_vector_type(4)));

// ===========================================================================
// GEMM: C[bt, e'] = sum_d x[bt,d] * W[e',d] + bias[e']   (all f32)
// (unchanged — verified absmax 0.0)
// ===========================================================================
__global__ __launch_bounds__(256, 2) void gemm_kernel(
    const float* __restrict__ x, const float* __restrict__ tau_w,
    const float* __restrict__ tau_b, const float* __restrict__ mem_w,
    const float* __restrict__ mem_b, float* __restrict__ xp, float* __restrict__ mm)
{
    __shared__ float As[32][132];
    __shared__ float Bs[32][68];

    const int tid  = threadIdx.x;
    const int bt0  = blockIdx.x * 128;
    const bool isxp = (blockIdx.y < 8);
    const float* W       = isxp ? tau_w : mem_w;
    const int    wstride = isxp ? 1024 : 512;
    const int    e0      = isxp ? blockIdx.y * 64 : blockIdx.y * 64 - 512;
    const float* bias    = isxp ? tau_b : mem_b;
    float*       dst     = isxp ? xp : mm;

    const int tm = tid & 31, tn = tid >> 5;
    const int lr = tid >> 3, lc = tid & 7;

    float bias_r[8];
#pragma unroll
    for (int ni = 0; ni < 8; ni++) bias_r[ni] = bias[e0 + tn * 8 + ni];

    float acc[4][8] = {};
    float4 pa[4], pb[2];

#pragma unroll
    for (int j = 0; j < 4; j++)
        pa[j] = *(const float4*)(x + (size_t)(bt0 + lr + 32 * j) * DD + lc * 4);
#pragma unroll
    for (int j = 0; j < 2; j++)
        pb[j] = *(const float4*)(W + (size_t)(e0 + lr + 32 * j) * wstride + lc * 4);

    for (int kb = 0; kb < DD; kb += 32) {
#pragma unroll
        for (int j = 0; j < 4; j++) {
            As[lc * 4 + 0][lr + 32 * j] = pa[j].x;
            As[lc * 4 + 1][lr + 32 * j] = pa[j].y;
            As[lc * 4 + 2][lr + 32 * j] = pa[j].z;
            As[lc * 4 + 3][lr + 32 * j] = pa[j].w;
        }
#pragma unroll
        for (int j = 0; j < 2; j++) {
            Bs[lc * 4 + 0][lr + 32 * j] = pb[j].x;
            Bs[lc * 4 + 1][lr + 32 * j] = pb[j].y;
            Bs[lc * 4 + 2][lr + 32 * j] = pb[j].z;
            Bs[lc * 4 + 3][lr + 32 * j] = pb[j].w;
        }
        __syncthreads();
        if (kb + 32 < DD) {
#pragma unroll
            for (int j = 0; j < 4; j++)
                pa[j] = *(const float4*)(x + (size_t)(bt0 + lr + 32 * j) * DD + kb + 32 + lc * 4);
#pragma unroll
            for (int j = 0; j < 2; j++)
                pb[j] = *(const float4*)(W + (size_t)(e0 + lr + 32 * j) * wstride + kb + 32 + lc * 4);
        }
#pragma unroll
        for (int k = 0; k < 32; k++) {
            float4 av  = *(const float4*)&As[k][tm * 4];
            float4 bv0 = *(const float4*)&Bs[k][tn * 8];
            float4 bv1 = *(const float4*)&Bs[k][tn * 8 + 4];
            float a_[4] = {av.x, av.y, av.z, av.w};
            float b_[8] = {bv0.x, bv0.y, bv0.z, bv0.w, bv1.x, bv1.y, bv1.z, bv1.w};
#pragma unroll
            for (int mi = 0; mi < 4; mi++)
#pragma unroll
                for (int ni = 0; ni < 8; ni++)
                    acc[mi][ni] = fmaf(a_[mi], b_[ni], acc[mi][ni]);
        }
        __syncthreads();
    }

#pragma unroll
    for (int mi = 0; mi < 4; mi++) {
        const int row = bt0 + tm * 4 + mi;
        float o[8];
#pragma unroll
        for (int ni = 0; ni < 8; ni++) o[ni] = __fadd_rn(acc[mi][ni], bias_r[ni]);
        float4 s0 = {o[0], o[1], o[2], o[3]};
        float4 s1 = {o[4], o[5], o[6], o[7]};
        *(float4*)(dst + (size_t)row * DD + e0 + tn * 8)     = s0;
        *(float4*)(dst + (size_t)row * DD + e0 + tn * 8 + 4) = s1;
    }
}

// ===========================================================================
// Scan: 4 WGs/batch, 256 WGs co-resident. Weights resident on-CU.
// DATA-AS-FLAG protocol: per-(producer->consumer) packed u64 slots, depth 2
// (step parity), sentinel-initialized. Producer fire-and-forget exchanges the
// packed pair; consumer poll-exchanges SENTINEL (read = auto-reset). Single
// MALL hop transports + signals; no flags, no fences, 2 barriers/step.
// ===========================================================================
__global__ __launch_bounds__(512, 1) void scan_kernel(
    const float* __restrict__ tau_w,
    float* __restrict__ xp_sp,          // out base: xp in, spikes out
    const float* __restrict__ mm,       // ws: m (B,T,D)
    const float* __restrict__ thrp,
    float* __restrict__ tau_out, float* __restrict__ v_out,
    unsigned long long* __restrict__ taug64)  // ws: sentinel-filled
{
    __shared__ float tau_lds[DD];
    __shared__ float partial[4][128];

    const int wg = blockIdx.x;
    const int b = wg >> 2, p = wg & 3;
    const int tid = threadIdx.x;
    const int w = tid >> 6, lane = tid & 63;
    const int c  = w & 3;                    // k-chunk
    const int le = ((w >> 2) << 6) + lane;   // 0..127
    const int ge = p * 128 + le;             // owned e

    // resident weights: Wt[ge][c*128 .. c*128+127] as 128 scalars
    float wv[128];
    {
        const float4* wrow = (const float4*)(tau_w + (size_t)ge * 1024 + 512 + c * 128);
#pragma unroll
        for (int j = 0; j < 32; j++) {
            float4 t = wrow[j];
            wv[4 * j + 0] = t.x; wv[4 * j + 1] = t.y;
            wv[4 * j + 2] = t.z; wv[4 * j + 3] = t.w;
        }
    }
#pragma unroll
    for (int j = 0; j < 128; j++) asm volatile("" : "+v"(wv[j]));  // keep live

    if (tid < DD) tau_lds[tid] = 1.0f;

    const float thr = thrp[0];
    const bool owner = (c == 0);             // waves 0 and 4
    float v = 0.0f, tau_keep = 1.0f;
    const size_t baseio = (size_t)b * TT * DD + ge;

    __syncthreads();

    for (int i = 0; i < TT; i++) {
        // prefetch step inputs (in flight during poll/dot)
        float xpv = 0.0f, mv = 0.0f;
        if (owner) {
            xpv = xp_sp[baseio + (size_t)i * DD];
            mv  = mm  [baseio + (size_t)i * DD];
        }

        if (i > 0 && tid < 192) {
            // poll-exchange: RMW at MALL; non-sentinel return == fresh data,
            // and the slot is auto-reset to sentinel for its next (i+2) use.
            const int s = tid >> 6, j = tid & 63;
            const int qsrc = (p + 1 + s) & 3;
            unsigned long long* slot =
                &taug64[(size_t)(i & 1) * (64 * 4 * 192) +
                        (size_t)(b * 4 + p) * 192 + s * 64 + j];
            unsigned long long pk;
            do {
                pk = __hip_atomic_exchange(slot, SENT, __ATOMIC_RELAXED,
                                           __HIP_MEMORY_SCOPE_AGENT);
            } while (pk == SENT);
            const int e0 = qsrc * 128 + 2 * j;
            tau_lds[e0]     = __uint_as_float((unsigned int)(pk & 0xFFFFFFFFu));
            tau_lds[e0 + 1] = __uint_as_float((unsigned int)(pk >> 32));
        }
        __syncthreads();   // A: gathered remote tau + prev owner tau visible

        float a0 = 0.f, a1 = 0.f, a2 = 0.f, a3 = 0.f;
        {
            const f4* tl = (const f4*)&tau_lds[c * 128];
#pragma unroll
            for (int j = 0; j < 32; j++) {
                f4 t4 = tl[j];                // wave-uniform addr -> broadcast
                a0 = fmaf(wv[4 * j + 0], t4.x, a0);
                a1 = fmaf(wv[4 * j + 1], t4.y, a1);
                a2 = fmaf(wv[4 * j + 2], t4.z, a2);
                a3 = fmaf(wv[4 * j + 3], t4.w, a3);
            }
        }
        partial[c][le] = (a0 + a1) + (a2 + a3);
        __syncthreads();   // B: partials complete; all dot reads of tau_lds done

        if (owner) {
            float dotv = (partial[0][le] + partial[1][le]) +
                         (partial[2][le] + partial[3][le]);
            float z     = __fadd_rn(xpv, dotv);
            float enz   = expf(-z);
            float tau_n = 1.0f / __fadd_rn(1.0f, enz);
            tau_keep = tau_n;

            // publish FIRST (cross-WG critical path), then local math
            tau_lds[ge] = tau_n;
            if (i < TT - 1) {
                float pf = __shfl_xor(tau_n, 1);
                if ((lane & 1) == 0) {
                    unsigned long long pk =
                        (unsigned long long)__float_as_uint(tau_n) |
                        ((unsigned long long)__float_as_uint(pf) << 32);
                    const int pl = le >> 1;
#pragma unroll
                    for (int s2 = 0; s2 < 3; s2++) {
                        const int q  = (p + 1 + s2) & 3;
                        const int sr = 2 - s2;          // (p - q - 1) & 3
                        __hip_atomic_exchange(
                            &taug64[(size_t)((i + 1) & 1) * (64 * 4 * 192) +
                                    (size_t)(b * 4 + q) * 192 + sr * 64 + pl],
                            pk, __ATOMIC_RELAXED, __HIP_MEMORY_SCOPE_AGENT);
                    }
                }
            }

            float tpe   = __fadd_rn(tau_n, 1e-6f);
            float alpha = expf(-1.0f / tpe);
            float vn = __fadd_rn(__fmul_rn(alpha, v),
                                 __fmul_rn(__fsub_rn(1.0f, alpha), mv));
            bool s = (vn >= thr);
            xp_sp[baseio + (size_t)i * DD] = s ? 1.0f : 0.0f;
            v = s ? 0.0f : vn;
        }
        // no barrier here: next iteration's gather only touches remote
        // tau_lds regions after barrier A; partial reuse guarded by A as well.
    }

    if (owner) {
        tau_out[b * DD + ge] = tau_keep;
        v_out  [b * DD + ge] = v;
    }
}

extern "C" void kernel_launch(void* const* d_in, const int* in_sizes, int n_in,
                              void* d_out, int out_size, void* d_ws, size_t ws_size,
                              hipStream_t stream) {
    (void)in_sizes; (void)n_in; (void)out_size; (void)ws_size;
    const float* x     = (const float*)d_in[0];
    const float* tau_w = (const float*)d_in[1];
    const float* tau_b = (const float*)d_in[2];
    const float* mem_w = (const float*)d_in[3];
    const float* mem_b = (const float*)d_in[4];
    const float* thr   = (const float*)d_in[5];
    float* out = (float*)d_out;

    float* mm                   = (float*)d_ws;
    unsigned long long* taug64  = (unsigned long long*)(mm + (size_t)BT * DD);

    // re-arm sentinels (harness poisons d_ws to 0xAA before each replay)
    hipMemsetAsync(taug64, 0xFF, TAUG_WORDS * sizeof(unsigned long long), stream);

    gemm_kernel<<<dim3(512, 16), 256, 0, stream>>>(x, tau_w, tau_b, mem_w, mem_b,
                                                   out, mm);
    scan_kernel<<<256, 512, 0, stream>>>(tau_w, out, mm, thr,
                                         out + (size_t)BT * DD,
                                         out + (size_t)BT * DD + (size_t)BB * DD,
                                         taug64);
}